// Round 7
// baseline (161.222 us; speedup 1.0000x reference)
//
#include <hip/hip_runtime.h>
#include <math.h>

#define DET 512
#define NB  16
#define NT  180
#define PI_D 3.14159265358979323846
#define NPAIR 89
#define PADQ 108
#define NGP  45                  // interleaved pair-rows gp=0..44 (col gp | col 88-gp)
#define PKI_ROW 1536             // dwords per pair-row: 768 entries x 2 (T,U)
#define NUNIT 113                // live transpose-pair units (16x16 tiles, a<=b)

// ws layout (bytes):
//   [0,712)        trigp float2[89]   symmetric pair trig (c,s)
//   [TT,+512K)     tth[d][k] f16      Toeplitz w[d-k] * 1024
//   [XF0,+32K)     xf0[b][512]  f32   filtered row t=0
//   [XF90,+32K)    xf90[b][512] f32   filtered row t=90
//   [PK,+4.3M)     pki[b][gp][1536] u32  interleaved {T[i],U[i]} packed f16 pairs
#define TT_OFF   8192
#define XF0_OFF  (TT_OFF + 512*512*2)
#define XF90_OFF (XF0_OFF + 32768)
#define PK_OFF   (XF90_OFF + 32768)

typedef _Float16 half8  __attribute__((ext_vector_type(8)));
typedef _Float16 half2v __attribute__((ext_vector_type(2)));
typedef float    float4v __attribute__((ext_vector_type(4)));

// f32 acc += f32 w * f16-half(pk)   (VOP3P mix, full-rate)
__device__ inline void fmix_lo(float& acc, float w, unsigned int pk) {
  asm("v_fma_mix_f32 %0, %1, %2, %0 op_sel_hi:[0,1,0]"
      : "+v"(acc) : "v"(w), "v"(pk));
}
__device__ inline void fmix_hi(float& acc, float w, unsigned int pk) {
  asm("v_fma_mix_f32 %0, %1, %2, %0 op_sel:[0,1,0] op_sel_hi:[0,1,0]"
      : "+v"(acc) : "v"(w), "v"(pk));
}

// ---------------- init: trig + scaled f16 Toeplitz table ----------------
__global__ __launch_bounds__(256) void init_kernel(char* __restrict__ wsb) {
  int tid = threadIdx.x;
  int d = blockIdx.x;
  _Float16* tth = (_Float16*)(wsb + TT_OFF);
#pragma unroll
  for (int c = 0; c < 2; c++) {
    int k = tid * 2 + c;
    int delta = d - k;
    float w;
    if (delta == 0) w = 0.5f;
    else if (delta & 1) { double dd = (double)delta; w = (float)(-2.0 / (PI_D * PI_D * dd * dd)); }
    else w = 0.f;
    tth[(size_t)d * 512 + k] = (_Float16)(w * 1024.0f);   // scale: avoid f16 denormals
  }
  if (d == 0 && tid < NPAIR) {
    float2* trigp = (float2*)wsb;
    int t = tid + 1, u = 179 - tid;
    float rt = (float)t * (float)(PI_D / 180.0);
    float ru = (float)u * (float)(PI_D / 180.0);
    double ct = cos((double)rt), st = sin((double)rt);
    double cu = cos((double)ru), su = sin((double)ru);
    float2 cs;
    cs.x = (float)((ct - cu) * 0.5);
    cs.y = (float)((st + su) * 0.5);
    trigp[tid] = cs;
  }
}

// ---------------- Filter (MFMA GEMM) + fused interleaved f16 pair-packing ----------------
__global__ __launch_bounds__(256) void filter_kernel(const float* __restrict__ x,
                                                     char* __restrict__ wsb) {
  __shared__ _Float16 xs_h[16][512];
  __shared__ _Float16 xs_l[16][512];
  __shared__ float xfs[16][65];
  const _Float16* tth = (const _Float16*)(wsb + TT_OFF);
  unsigned int* pkg = (unsigned int*)(wsb + PK_OFF);

  int tid = threadIdx.x;
  int p = blockIdx.x, b = blockIdx.y;
  int dt0 = blockIdx.z * 2;

  int m = tid & 15, kp = tid >> 4;
  int tS;
  if (p < 11) tS = (m < 8) ? (8 * p + 1 + m) : (164 - 8 * p + m);
  else        tS = (m == 0) ? 89 : ((m == 1) ? 91 : ((m == 3) ? 90 : 0));
  const float* xb = x + (size_t)b * DET * NT + tS;
#pragma unroll 8
  for (int pass = 0; pass < 16; pass++) {
    int k = pass * 32 + kp * 2;
    int c = k >> 3, h = k & 7;
    int phys = (((c ^ (m & 7)) << 3) | h);
    float v0 = xb[(size_t)k * NT];
    float v1 = xb[(size_t)(k + 1) * NT];
    _Float16 h0 = (_Float16)v0, h1 = (_Float16)v1;
    half2v hh = {h0, h1};
    half2v ll = {(_Float16)(v0 - (float)h0), (_Float16)(v1 - (float)h1)};
    *(half2v*)&xs_h[m][phys] = hh;
    *(half2v*)&xs_l[m][phys] = ll;
  }
  __syncthreads();

  int nprb = (p < 11) ? 8 : 1;
  int tpb0 = (p < 11) ? 8 * p : 88;
  if (blockIdx.z == 0) {
    // zero pad entries [0,108) and [620,768) for both slots (uint2 per entry)
    int idx = (tid < 108) ? tid : (620 + (tid - 108));
    uint2 z2; z2.x = 0u; z2.y = 0u;
    for (int pr = 0; pr < nprb; pr++) {
      int tq = (p < 11) ? (tpb0 + pr) : 88;
      int gp = (tq <= 44) ? tq : 88 - tq;
      *(uint2*)&pkg[((size_t)b * NGP + gp) * PKI_ROW + 2 * idx] = z2;
    }
  }

  int lane = tid & 63, wv = tid >> 6;
  int mm = lane & 15, q = lane >> 4;
  const _Float16* arh = &xs_h[mm][0];
  const _Float16* arl = &xs_l[mm][0];
  int e = mm & 7;
  int mp = tid >> 5, cc = (tid & 31) * 2;
  int rT = (p < 11) ? mp : 0;
  int rU = (p < 11) ? (15 - mp) : 1;
  int tpp = (p < 11) ? (8 * p + mp) : 88;
  bool dopack = (p < 11) || (mp == 0);
  int gp_  = (tpp <= 44) ? tpp : 88 - tpp;
  int slot = (tpp <= 44) ? 0 : 1;

  for (int dti = 0; dti < 2; dti++) {
    int dt = dt0 + dti;
    int dw = dt * 64 + wv * 16 + mm;
    const _Float16* th = tth + (size_t)dw * 512;
    float4v acc0 = {0.f, 0.f, 0.f, 0.f};
    float4v acc1 = {0.f, 0.f, 0.f, 0.f};
#pragma unroll 4
    for (int kc = 0; kc < 512; kc += 32) {
      int ph = ((((kc >> 3) + q) ^ e) << 3);
      half8 Ah = *(const half8*)&arh[ph];
      half8 Al = *(const half8*)&arl[ph];
      half8 Bh = *(const half8*)&th[kc + q * 8];
      acc0 = __builtin_amdgcn_mfma_f32_16x16x32_f16(Ah, Bh, acc0, 0, 0, 0);
      acc1 = __builtin_amdgcn_mfma_f32_16x16x32_f16(Al, Bh, acc1, 0, 0, 0);
    }
    if (dti > 0) __syncthreads();
#pragma unroll
    for (int i = 0; i < 4; i++)
      xfs[q * 4 + i][wv * 16 + mm] = (acc0[i] + acc1[i]) * 0.0009765625f;
    __syncthreads();
    if (dopack) {
      float ft0 = xfs[rT][cc], ft1 = xfs[rT][cc + 1];
      float fu0 = xfs[rU][cc], fu1 = xfs[rU][cc + 1];
      auto p0 = __builtin_amdgcn_cvt_pkrtz(ft0, fu0);   // lo=ft, hi=fu
      auto p1 = __builtin_amdgcn_cvt_pkrtz(ft1, fu1);
      unsigned int w0, w1;
      __builtin_memcpy(&w0, &p0, 4);
      __builtin_memcpy(&w1, &p1, 4);
      unsigned int* row = pkg + ((size_t)b * NGP + gp_) * PKI_ROW;
      int en = PADQ + dt * 64 + cc;
      row[2 * en + slot]     = w0;
      row[2 * en + 2 + slot] = w1;
      if (tpp == 44) {               // self-paired row: duplicate into slot 1
        row[2 * en + 1] = w0;
        row[2 * en + 3] = w1;
      }
    }
    if (p == 11 && tid < 64) {         // singles: row2=t0, row3=t90
      float* f0  = (float*)(wsb + XF0_OFF)  + (size_t)b * DET;
      float* f90 = (float*)(wsb + XF90_OFF) + (size_t)b * DET;
      f0[dt * 64 + tid]  = xfs[2][tid];
      f90[dt * 64 + tid] = xfs[3][tid];
    }
  }
}

// ---------------- Backprojection v14: hardened counted-vmcnt pipeline ----------------
// (R7 = R6 resubmit; R6 run was an infra failure, kernel never executed.)
// vs failed v13: (1) 4B DMA chunks (HW-measured width; 24 chunks = uniform 6
// instrs/wave -> per-wave vmcnt arithmetic is exact); (2) pre-barrier wait is
// "vmcnt(6) lgkmcnt(0)" — counted on vm (stage g+2 stays in flight across the
// barrier) but FULL lgkm drain (kills the pending-ds_read WAR race that NaN'd
// v13); (3) __builtin_amdgcn_s_barrier (verified 8-phase pattern), sched_barrier
// fenced. Tile g's DMA confirmed at end of iter g-1; WAR (stage g+2 overwrites
// buf read at g-1) ordered by the barrier.
#define PIPE_BARRIER(N)                                                        \
  asm volatile("s_waitcnt vmcnt(" #N ") lgkmcnt(0)" ::: "memory");             \
  __builtin_amdgcn_sched_barrier(0);                                           \
  __builtin_amdgcn_s_barrier();                                                \
  __builtin_amdgcn_sched_barrier(0);

#define PROCESS(c_, s_, SW)                                                    \
  {                                                                            \
    float inner = fmaf(-(s_), q_, 363.5f);                                     \
    float iyA = fmaf( (c_), p_, inner);                                        \
    float iyB = fmaf(-(c_), p_, inner);                                        \
    int   iA = (int)iyA;  float wA = __builtin_amdgcn_fractf(iyA);             \
    int   iB = (int)iyB;  float wB = __builtin_amdgcn_fractf(iyB);             \
    float vA = 1.f - wA, vB = 1.f - wB;                                        \
    uint4 rA, rB, rMA, rMB;                                                    \
    __builtin_memcpy(&rA,  &colI[2 * iA], 16);                                 \
    __builtin_memcpy(&rB,  &colI[2 * iB], 16);                                 \
    __builtin_memcpy(&rMA, &colI[2 * (726 - iA)], 16);                         \
    __builtin_memcpy(&rMB, &colI[2 * (726 - iB)], 16);                         \
    unsigned tA0 = SW ? rA.y : rA.x,  tA1 = SW ? rA.w : rA.z;                  \
    unsigned uA0 = SW ? rA.x : rA.y,  uA1 = SW ? rA.z : rA.w;                  \
    unsigned tB0 = SW ? rB.y : rB.x,  tB1 = SW ? rB.w : rB.z;                  \
    unsigned uB0 = SW ? rB.x : rB.y,  uB1 = SW ? rB.z : rB.w;                  \
    unsigned tMA0 = SW ? rMA.y : rMA.x,  tMA1 = SW ? rMA.w : rMA.z;            \
    unsigned uMA0 = SW ? rMA.x : rMA.y,  uMA1 = SW ? rMA.z : rMA.w;            \
    unsigned tMB0 = SW ? rMB.y : rMB.x,  tMB1 = SW ? rMB.w : rMB.z;            \
    unsigned uMB0 = SW ? rMB.x : rMB.y,  uMB1 = SW ? rMB.z : rMB.w;            \
    fmix_lo(A1, vA, tA0);  fmix_lo(A1, wA, tA1);                               \
    fmix_hi(A1, vB, tB0);  fmix_hi(A1, wB, tB1);                               \
    fmix_lo(A2, vB, tB0);  fmix_lo(A2, wB, tB1);                               \
    fmix_hi(A2, vA, tA0);  fmix_hi(A2, wA, tA1);                               \
    fmix_lo(A3, wA, tMA0); fmix_lo(A3, vA, tMA1);                              \
    fmix_hi(A3, wB, tMB0); fmix_hi(A3, vB, tMB1);                              \
    fmix_lo(A4, wB, tMB0); fmix_lo(A4, vB, tMB1);                              \
    fmix_hi(A4, wA, tMA0); fmix_hi(A4, vA, tMA1);                              \
    if (doQ) {                                                                 \
      fmix_lo(B1, wA, uMA0); fmix_lo(B1, vA, uMA1);                            \
      fmix_hi(B1, vB, uB0);  fmix_hi(B1, wB, uB1);                             \
      fmix_lo(B2, wB, uMB0); fmix_lo(B2, vB, uMB1);                            \
      fmix_hi(B2, vA, uA0);  fmix_hi(B2, wA, uA1);                             \
      fmix_lo(B3, vA, uA0);  fmix_lo(B3, wA, uA1);                             \
      fmix_hi(B3, wB, uMB0); fmix_hi(B3, vB, uMB1);                            \
      fmix_lo(B4, vB, uB0);  fmix_lo(B4, wB, uB1);                             \
      fmix_hi(B4, wA, uMA0); fmix_hi(B4, vA, uMA1);                            \
    }                                                                          \
  }

__global__ __launch_bounds__(256, 8) void backproj_kernel(
    const char* __restrict__ wsb, float* __restrict__ out) {
  __shared__ unsigned int pk[3][PKI_ROW];   // 18432 B (3-buffer rotation)
  __shared__ float2 trigs[NGP + 1];         // trig via LDS: no VMEM in main loop
  int tid = threadIdx.x;
  int b   = blockIdx.y;
  int bx  = blockIdx.x;
  int lx = tid & 15, ly = tid >> 4;
  float* ob = out + (size_t)b * DET * DET;

  if (bx == NUNIT) {
    // zero dead 16x16 tiles (a, bt<L[a]) and their 3 mirrors; no barriers here
    const int LDEAD[10] = {10,8,6,5,4,3,2,2,1,1};
    for (int a = 0; a < 10; a++)
      for (int bt = 0; bt < LDEAD[a]; bt++) {
        int X1 = 16*a + lx, X2 = 511 - X1;
        int Y1 = 16*bt + ly, Y2 = 511 - Y1;
        ob[(size_t)Y1*DET + X1] = 0.f;
        ob[(size_t)Y1*DET + X2] = 0.f;
        ob[(size_t)Y2*DET + X1] = 0.f;
        ob[(size_t)Y2*DET + X2] = 0.f;
      }
    return;
  }

  // unit decode: a via cumulative table, bt = bx - S[a] + bstart[a]
  int a = (bx>=6)+(bx>=14)+(bx>=24)+(bx>=35)+(bx>=47)+(bx>=58)+(bx>=68)
        + (bx>=77)+(bx>=85)+(bx>=92)+(bx>=98)+(bx>=103)+(bx>=107)+(bx>=110)+(bx>=112);
  int Sa, bs;
  if (a < 8) { Sa = (int)((0x443A2F23180E0600ULL >> (8*a)) & 0xFF);
               bs = (int)((0x070605040506080AULL >> (8*a)) & 0xFF); }
  else       { Sa = (int)((0x706E6B67625C554DULL >> (8*(a-8))) & 0xFF);
               bs = (int)((0x0F0E0D0C0B0A0908ULL >> (8*(a-8))) & 0xFF); }
  int bt = bx - Sa + bs;
  bool doQ = (a != bt);
  int tx = 16*a, ty = 16*bt;

  int X1 = tx + lx, X2 = 511 - X1;
  int Y1 = ty + ly, Y2 = 511 - Y1;
  float p_ = (float)X1 - 255.5f;
  float q_ = (float)Y1 - 255.5f;

  int w = tid >> 6, l = tid & 63;
  int mkx = 481 - 32*a;
  int mky = 505 - 32*bt - 8*w;          // min |ky| over this wave's 4 rows
  bool wlive = (mkx*mkx + mky*mky <= 261632);   // symmetric: covers P and Q sets

  if (tid < NGP) trigs[tid] = ((const float2*)wsb)[tid];

  const unsigned int* pkg = (const unsigned int*)(wsb + PK_OFF) + (size_t)b * NGP * PKI_ROW;

  float A1=0.f, A2=0.f, A3=0.f, A4=0.f;   // P-tile mirrors
  float B1=0.f, B2=0.f, B3=0.f, B4=0.f;   // Q (transposed) tile mirrors

  // stage pair-row g (6144 B) into pk[g%3]: 24 chunks of 256B (4B/lane, measured
  // width) = UNIFORM 6 DMA instrs per wave -> per-wave counted vmcnt is exact.
  auto stage_group = [&](int g) {
    const char* srcb = (const char*)(pkg + (size_t)g * PKI_ROW);
    char* dstb = (char*)&pk[g % 3][0];
#pragma unroll
    for (int i = 0; i < 6; i++) {
      int c = w * 6 + i;
      __builtin_amdgcn_global_load_lds(
          (const __attribute__((address_space(1))) unsigned int*)(srcb + c * 256 + l * 4),
          (__attribute__((address_space(3))) unsigned int*)(dstb + c * 256),
          4, 0, 0);
    }
  };

  stage_group(0);
  stage_group(1);
  __syncthreads();           // one-time full drain: trig + buf0 + buf1 ready

  for (int g = 0; g < NGP; g++) {
    if (g + 2 < NGP) stage_group(g + 2);
    float2 cs = trigs[g];
    const unsigned int* colI = &pk[g % 3][0];
    if (wlive) {
      PROCESS(cs.x, cs.y, 0);                    // tp = g      (P=slot0, Q=slot1)
      if (g != 44) PROCESS(cs.y, cs.x, 1);       // tp = 88-g   (P=slot1, Q=slot0)
    }
    // counted-vmcnt barrier: this iter's 6 DMAs stay in flight; previous iter's
    // stage (tile g+1) is guaranteed landed; all local ds_reads drained (lgkm 0).
    if (g + 2 < NGP) { PIPE_BARRIER(6) } else { PIPE_BARRIER(0) }
  }

  // epilogue: singles t=0 / t=90, mask, scale
  const float* f0  = (const float*)(wsb + XF0_OFF)  + (size_t)b * DET;
  const float* f90 = (const float*)(wsb + XF90_OFF) + (size_t)b * DET;
  const float SC = (float)(PI_D / 360.0);
  int kx = 2*X1 - 511, ky = 2*Y1 - 511;
  bool in = (kx*kx + ky*ky) <= 261632;            // symmetric across all 8 outputs

  float g0x1 = f0[X1], g0x2 = f0[X2];
  float g90y1 = f90[Y1], g90y2 = f90[Y2];
  float P1 = A1 + g0x1 + g90y2;
  float P2 = A2 + g0x2 + g90y2;
  float P3 = A3 + g0x2 + g90y1;
  float P4 = A4 + g0x1 + g90y1;
  ob[(size_t)Y1*DET + X1] = in ? P1*SC : 0.f;
  ob[(size_t)Y1*DET + X2] = in ? P2*SC : 0.f;
  ob[(size_t)Y2*DET + X2] = in ? P3*SC : 0.f;
  ob[(size_t)Y2*DET + X1] = in ? P4*SC : 0.f;

  if (doQ) {
    float g0y1 = f0[Y1], g0y2 = f0[Y2];
    float g90x1 = f90[X1], g90x2 = f90[X2];
    float Q1 = B1 + g0y1 + g90x2;
    float Q2 = B2 + g0y1 + g90x1;
    float Q3 = B3 + g0y2 + g90x1;
    float Q4 = B4 + g0y2 + g90x2;
    Q1 = in ? Q1*SC : 0.f;
    Q2 = in ? Q2*SC : 0.f;
    Q3 = in ? Q3*SC : 0.f;
    Q4 = in ? Q4*SC : 0.f;
    __syncthreads();                                // pk free now
    float* qs = (float*)&pk[0][0];                  // [4][16][17] padded
    qs[(0*16 + lx)*17 + ly] = Q1;
    qs[(1*16 + lx)*17 + ly] = Q2;
    qs[(2*16 + lx)*17 + ly] = Q3;
    qs[(3*16 + lx)*17 + ly] = Q4;
    __syncthreads();
    float o1 = qs[(0*16 + ly)*17 + lx];
    float o2 = qs[(1*16 + ly)*17 + lx];
    float o3 = qs[(2*16 + ly)*17 + lx];
    float o4 = qs[(3*16 + ly)*17 + lx];
    int r1 = tx + ly, r2 = 511 - r1;
    int c1 = ty + lx, c2 = 511 - c1;
    ob[(size_t)r1*DET + c1] = o1;   // Q1: rows X1, cols Y1
    ob[(size_t)r2*DET + c1] = o2;   // Q2: rows X2, cols Y1
    ob[(size_t)r2*DET + c2] = o3;   // Q3: rows X2, cols Y2
    ob[(size_t)r1*DET + c2] = o4;   // Q4: rows X1, cols Y2
  }
}

extern "C" void kernel_launch(void* const* d_in, const int* in_sizes, int n_in,
                              void* d_out, int out_size, void* d_ws, size_t ws_size,
                              hipStream_t stream) {
  (void)in_sizes; (void)n_in; (void)out_size; (void)ws_size;
  const float* x = (const float*)d_in[0];
  float* out = (float*)d_out;
  char*  wsb = (char*)d_ws;

  init_kernel<<<512, 256, 0, stream>>>(wsb);
  filter_kernel<<<dim3(12, 16, 4), 256, 0, stream>>>(x, wsb);
  backproj_kernel<<<dim3(NUNIT + 1, 16), 256, 0, stream>>>(wsb, out);
}

// Round 8
// 142.065 us; speedup vs baseline: 1.1348x; 1.1348x over previous
//
#include <hip/hip_runtime.h>
#include <math.h>

#define DET 512
#define NB  16
#define NT  180
#define PI_D 3.14159265358979323846
#define NPAIR 89
#define PADQ 108
#define NGP  45                  // interleaved pair-rows gp=0..44 (col gp | col 88-gp)
#define PKI_ROW 1536             // dwords per pair-row: 768 entries x 2 (T,U)
#define NUNIT 113                // live transpose-pair units (16x16 tiles, a<=b)

// ws layout (bytes):
//   [0,8192)       (unused; was trig+pad)
//   [TT,+512K)     (unused; Toeplitz now computed in-LDS by filter)
//   [XF0,+32K)     xf0[b][512]  f32   filtered row t=0
//   [XF90,+32K)    xf90[b][512] f32   filtered row t=90
//   [PK,+4.3M)     pki[b][gp][1536] u32  interleaved {T[i],U[i]} packed f16 pairs
#define TT_OFF   8192
#define XF0_OFF  (TT_OFF + 512*512*2)
#define XF90_OFF (XF0_OFF + 32768)
#define PK_OFF   (XF90_OFF + 32768)

typedef _Float16 half8  __attribute__((ext_vector_type(8)));
typedef _Float16 half4v __attribute__((ext_vector_type(4)));
typedef _Float16 half2v __attribute__((ext_vector_type(2)));
typedef float    float4v __attribute__((ext_vector_type(4)));

// f32 acc += f32 w * f16-half(pk)   (VOP3P mix, full-rate)
__device__ inline void fmix_lo(float& acc, float w, unsigned int pk) {
  asm("v_fma_mix_f32 %0, %1, %2, %0 op_sel_hi:[0,1,0]"
      : "+v"(acc) : "v"(w), "v"(pk));
}
__device__ inline void fmix_hi(float& acc, float w, unsigned int pk) {
  asm("v_fma_mix_f32 %0, %1, %2, %0 op_sel:[0,1,0] op_sel_hi:[0,1,0]"
      : "+v"(acc) : "v"(w), "v"(pk));
}

// ---------------- Filter (MFMA GEMM) + fused interleaved f16 pair-packing ----------------
// R8: Toeplitz B-operand from LDS shift-copies (wls[8][1032]) instead of a global
// 512KB table: wls[r][k] = w[511-k-r]*1024 (f16). B-fragment for row dw at kc:
// base = &wls[(511-dw)&7][(511-dw)&~7], Bh = base[kc+q*8 .. +7] — 16B-aligned
// ds_read_b128, identical values to the old tth read. init_kernel is deleted.
__global__ __launch_bounds__(256) void filter_kernel(const float* __restrict__ x,
                                                     char* __restrict__ wsb) {
  __shared__ _Float16 xs_h[16][512];
  __shared__ _Float16 xs_l[16][512];
  __shared__ float xfs[16][65];
  __shared__ _Float16 wls[8][1032];      // 8 shift-copies, 2064B row (16B-mult)
  unsigned int* pkg = (unsigned int*)(wsb + PK_OFF);

  int tid = threadIdx.x;
  int p = blockIdx.x, b = blockIdx.y;
  int dt0 = blockIdx.z * 2;

  // ---- fill Toeplitz shift-copies: thread fills 4 consecutive k for each r ----
  {
    int k0 = tid * 4;
    const float CSC = (float)(-2048.0 / (PI_D * PI_D));   // (w*1024) numerator
#pragma unroll
    for (int r = 0; r < 8; r++) {
      half4v v;
#pragma unroll
      for (int j = 0; j < 4; j++) {
        int delta = 511 - (k0 + j) - r;
        float wv;
        if (delta == 0) wv = 512.0f;                       // 0.5 * 1024
        else if (delta & 1) wv = CSC / (float)(delta * delta);
        else wv = 0.0f;
        v[j] = (_Float16)wv;
      }
      *(half4v*)&wls[r][k0] = v;
    }
  }

  int m = tid & 15, kp = tid >> 4;
  int tS;
  if (p < 11) tS = (m < 8) ? (8 * p + 1 + m) : (164 - 8 * p + m);
  else        tS = (m == 0) ? 89 : ((m == 1) ? 91 : ((m == 3) ? 90 : 0));
  const float* xb = x + (size_t)b * DET * NT + tS;
#pragma unroll 8
  for (int pass = 0; pass < 16; pass++) {
    int k = pass * 32 + kp * 2;
    int c = k >> 3, h = k & 7;
    int phys = (((c ^ (m & 7)) << 3) | h);
    float v0 = xb[(size_t)k * NT];
    float v1 = xb[(size_t)(k + 1) * NT];
    _Float16 h0 = (_Float16)v0, h1 = (_Float16)v1;
    half2v hh = {h0, h1};
    half2v ll = {(_Float16)(v0 - (float)h0), (_Float16)(v1 - (float)h1)};
    *(half2v*)&xs_h[m][phys] = hh;
    *(half2v*)&xs_l[m][phys] = ll;
  }
  __syncthreads();   // covers xs staging AND wls fill

  int nprb = (p < 11) ? 8 : 1;
  int tpb0 = (p < 11) ? 8 * p : 88;
  if (blockIdx.z == 0) {
    // zero pad entries [0,108) and [620,768) for both slots (uint2 per entry)
    int idx = (tid < 108) ? tid : (620 + (tid - 108));
    uint2 z2; z2.x = 0u; z2.y = 0u;
    for (int pr = 0; pr < nprb; pr++) {
      int tq = (p < 11) ? (tpb0 + pr) : 88;
      int gp = (tq <= 44) ? tq : 88 - tq;
      *(uint2*)&pkg[((size_t)b * NGP + gp) * PKI_ROW + 2 * idx] = z2;
    }
  }

  int lane = tid & 63, wv = tid >> 6;
  int mm = lane & 15, q = lane >> 4;
  const _Float16* arh = &xs_h[mm][0];
  const _Float16* arl = &xs_l[mm][0];
  int e = mm & 7;
  int mp = tid >> 5, cc = (tid & 31) * 2;
  int rT = (p < 11) ? mp : 0;
  int rU = (p < 11) ? (15 - mp) : 1;
  int tpp = (p < 11) ? (8 * p + mp) : 88;
  bool dopack = (p < 11) || (mp == 0);
  int gp_  = (tpp <= 44) ? tpp : 88 - tpp;
  int slot = (tpp <= 44) ? 0 : 1;

  for (int dti = 0; dti < 2; dti++) {
    int dt = dt0 + dti;
    int dw = dt * 64 + wv * 16 + mm;
    int sdw = 511 - dw;
    const _Float16* thl = &wls[sdw & 7][sdw & ~7];   // 16B-aligned per-lane base
    float4v acc0 = {0.f, 0.f, 0.f, 0.f};
    float4v acc1 = {0.f, 0.f, 0.f, 0.f};
#pragma unroll 4
    for (int kc = 0; kc < 512; kc += 32) {
      int ph = ((((kc >> 3) + q) ^ e) << 3);
      half8 Ah = *(const half8*)&arh[ph];
      half8 Al = *(const half8*)&arl[ph];
      half8 Bh = *(const half8*)&thl[kc + q * 8];
      acc0 = __builtin_amdgcn_mfma_f32_16x16x32_f16(Ah, Bh, acc0, 0, 0, 0);
      acc1 = __builtin_amdgcn_mfma_f32_16x16x32_f16(Al, Bh, acc1, 0, 0, 0);
    }
    if (dti > 0) __syncthreads();
#pragma unroll
    for (int i = 0; i < 4; i++)
      xfs[q * 4 + i][wv * 16 + mm] = (acc0[i] + acc1[i]) * 0.0009765625f;
    __syncthreads();
    if (dopack) {
      float ft0 = xfs[rT][cc], ft1 = xfs[rT][cc + 1];
      float fu0 = xfs[rU][cc], fu1 = xfs[rU][cc + 1];
      auto p0 = __builtin_amdgcn_cvt_pkrtz(ft0, fu0);   // lo=ft, hi=fu
      auto p1 = __builtin_amdgcn_cvt_pkrtz(ft1, fu1);
      unsigned int w0, w1;
      __builtin_memcpy(&w0, &p0, 4);
      __builtin_memcpy(&w1, &p1, 4);
      unsigned int* row = pkg + ((size_t)b * NGP + gp_) * PKI_ROW;
      int en = PADQ + dt * 64 + cc;
      row[2 * en + slot]     = w0;
      row[2 * en + 2 + slot] = w1;
      if (tpp == 44) {               // self-paired row: duplicate into slot 1
        row[2 * en + 1] = w0;
        row[2 * en + 3] = w1;
      }
    }
    if (p == 11 && tid < 64) {         // singles: row2=t0, row3=t90
      float* f0  = (float*)(wsb + XF0_OFF)  + (size_t)b * DET;
      float* f90 = (float*)(wsb + XF90_OFF) + (size_t)b * DET;
      f0[dt * 64 + tid]  = xfs[2][tid];
      f90[dt * 64 + tid] = xfs[3][tid];
    }
  }
}

// ---------------- Backprojection v12r: interleaved pair-columns (R4 core) ----------------
// EXACT R4-v12 structure (84.1 µs measured): pk[2] double-buffer, 16B-chunk DMA,
// __syncthreads per g. Counted-vmcnt (v13/v14) regressed — drain was already
// covered; 4B staging cost dominated. Only change: trig computed in-prologue
// (pair trig reduces to (cos t°, sin t°)), so no init kernel / no global trig.
#define PROCESS(c_, s_, SW)                                                    \
  {                                                                            \
    float inner = fmaf(-(s_), q_, 363.5f);                                     \
    float iyA = fmaf( (c_), p_, inner);                                        \
    float iyB = fmaf(-(c_), p_, inner);                                        \
    int   iA = (int)iyA;  float wA = __builtin_amdgcn_fractf(iyA);             \
    int   iB = (int)iyB;  float wB = __builtin_amdgcn_fractf(iyB);             \
    float vA = 1.f - wA, vB = 1.f - wB;                                        \
    uint4 rA, rB, rMA, rMB;                                                    \
    __builtin_memcpy(&rA,  &colI[2 * iA], 16);                                 \
    __builtin_memcpy(&rB,  &colI[2 * iB], 16);                                 \
    __builtin_memcpy(&rMA, &colI[2 * (726 - iA)], 16);                         \
    __builtin_memcpy(&rMB, &colI[2 * (726 - iB)], 16);                         \
    unsigned tA0 = SW ? rA.y : rA.x,  tA1 = SW ? rA.w : rA.z;                  \
    unsigned uA0 = SW ? rA.x : rA.y,  uA1 = SW ? rA.z : rA.w;                  \
    unsigned tB0 = SW ? rB.y : rB.x,  tB1 = SW ? rB.w : rB.z;                  \
    unsigned uB0 = SW ? rB.x : rB.y,  uB1 = SW ? rB.z : rB.w;                  \
    unsigned tMA0 = SW ? rMA.y : rMA.x,  tMA1 = SW ? rMA.w : rMA.z;            \
    unsigned uMA0 = SW ? rMA.x : rMA.y,  uMA1 = SW ? rMA.z : rMA.w;            \
    unsigned tMB0 = SW ? rMB.y : rMB.x,  tMB1 = SW ? rMB.w : rMB.z;            \
    unsigned uMB0 = SW ? rMB.x : rMB.y,  uMB1 = SW ? rMB.z : rMB.w;            \
    fmix_lo(A1, vA, tA0);  fmix_lo(A1, wA, tA1);                               \
    fmix_hi(A1, vB, tB0);  fmix_hi(A1, wB, tB1);                               \
    fmix_lo(A2, vB, tB0);  fmix_lo(A2, wB, tB1);                               \
    fmix_hi(A2, vA, tA0);  fmix_hi(A2, wA, tA1);                               \
    fmix_lo(A3, wA, tMA0); fmix_lo(A3, vA, tMA1);                              \
    fmix_hi(A3, wB, tMB0); fmix_hi(A3, vB, tMB1);                              \
    fmix_lo(A4, wB, tMB0); fmix_lo(A4, vB, tMB1);                              \
    fmix_hi(A4, wA, tMA0); fmix_hi(A4, vA, tMA1);                              \
    if (doQ) {                                                                 \
      fmix_lo(B1, wA, uMA0); fmix_lo(B1, vA, uMA1);                            \
      fmix_hi(B1, vB, uB0);  fmix_hi(B1, wB, uB1);                             \
      fmix_lo(B2, wB, uMB0); fmix_lo(B2, vB, uMB1);                            \
      fmix_hi(B2, vA, uA0);  fmix_hi(B2, wA, uA1);                             \
      fmix_lo(B3, vA, uA0);  fmix_lo(B3, wA, uA1);                             \
      fmix_hi(B3, wB, uMB0); fmix_hi(B3, vB, uMB1);                            \
      fmix_lo(B4, vB, uB0);  fmix_lo(B4, wB, uB1);                             \
      fmix_hi(B4, wA, uMA0); fmix_hi(B4, vA, uMA1);                            \
    }                                                                          \
  }

__global__ __launch_bounds__(256, 8) void backproj_kernel(
    const char* __restrict__ wsb, float* __restrict__ out) {
  __shared__ unsigned int pk[2][PKI_ROW];   // 12288 B; epilogue-aliased as qs
  __shared__ float2 trigs[48];
  int tid = threadIdx.x;
  int b   = blockIdx.y;
  int bx  = blockIdx.x;
  int lx = tid & 15, ly = tid >> 4;
  float* ob = out + (size_t)b * DET * DET;

  if (bx == NUNIT) {
    // zero dead 16x16 tiles (a, bt<L[a]) and their 3 mirrors
    const int LDEAD[10] = {10,8,6,5,4,3,2,2,1,1};
    for (int a = 0; a < 10; a++)
      for (int bt = 0; bt < LDEAD[a]; bt++) {
        int X1 = 16*a + lx, X2 = 511 - X1;
        int Y1 = 16*bt + ly, Y2 = 511 - Y1;
        ob[(size_t)Y1*DET + X1] = 0.f;
        ob[(size_t)Y1*DET + X2] = 0.f;
        ob[(size_t)Y2*DET + X1] = 0.f;
        ob[(size_t)Y2*DET + X2] = 0.f;
      }
    return;
  }

  // unit decode: a via cumulative table, bt = bx - S[a] + bstart[a]
  int a = (bx>=6)+(bx>=14)+(bx>=24)+(bx>=35)+(bx>=47)+(bx>=58)+(bx>=68)
        + (bx>=77)+(bx>=85)+(bx>=92)+(bx>=98)+(bx>=103)+(bx>=107)+(bx>=110)+(bx>=112);
  int Sa, bs;
  if (a < 8) { Sa = (int)((0x443A2F23180E0600ULL >> (8*a)) & 0xFF);
               bs = (int)((0x070605040506080AULL >> (8*a)) & 0xFF); }
  else       { Sa = (int)((0x706E6B67625C554DULL >> (8*(a-8))) & 0xFF);
               bs = (int)((0x0F0E0D0C0B0A0908ULL >> (8*(a-8))) & 0xFF); }
  int bt = bx - Sa + bs;
  bool doQ = (a != bt);
  int tx = 16*a, ty = 16*bt;

  int X1 = tx + lx, X2 = 511 - X1;
  int Y1 = ty + ly, Y2 = 511 - Y1;
  float p_ = (float)X1 - 255.5f;
  float q_ = (float)Y1 - 255.5f;

  int w = tid >> 6, l = tid & 63;
  int mkx = 481 - 32*a;
  int mky = 505 - 32*bt - 8*w;          // min |ky| over this wave's 4 rows
  bool wlive = (mkx*mkx + mky*mky <= 261632);   // symmetric: covers P and Q sets

  // pair trig (ct - cu)/2 = cos t, (st + su)/2 = sin t for u = 180 - t
  if (tid < NGP) {
    float th = (float)(tid + 1) * (float)(PI_D / 180.0);
    float2 cs; cs.x = cosf(th); cs.y = sinf(th);
    trigs[tid] = cs;
  }

  const unsigned int* pkg = (const unsigned int*)(wsb + PK_OFF) + (size_t)b * NGP * PKI_ROW;

  float A1=0.f, A2=0.f, A3=0.f, A4=0.f;   // P-tile mirrors
  float B1=0.f, B2=0.f, B3=0.f, B4=0.f;   // Q (transposed) tile mirrors

  // stage pair-row gp (6144 B): 6 chunks of 1024B over 4 waves (16B/lane DMA)
  auto stage_group = [&](int g, int par) {
    {
      const unsigned int* src = pkg + (size_t)g * PKI_ROW + w * 256 + l * 4;
      char* dst = (char*)&pk[par][0] + w * 1024;
      __builtin_amdgcn_global_load_lds(
          (const __attribute__((address_space(1))) unsigned int*)src,
          (__attribute__((address_space(3))) unsigned int*)dst, 16, 0, 0);
    }
    if (w < 2) {
      const unsigned int* src = pkg + (size_t)g * PKI_ROW + (w + 4) * 256 + l * 4;
      char* dst = (char*)&pk[par][0] + (w + 4) * 1024;
      __builtin_amdgcn_global_load_lds(
          (const __attribute__((address_space(1))) unsigned int*)src,
          (__attribute__((address_space(3))) unsigned int*)dst, 16, 0, 0);
    }
  };

  stage_group(0, 0);
  __syncthreads();   // covers stage(0) AND trigs fill

  for (int g = 0; g < NGP; g++) {
    if (g + 1 < NGP) stage_group(g + 1, (g + 1) & 1);
    float2 cs = trigs[g];
    const unsigned int* colI = &pk[g & 1][0];
    if (wlive) {
      PROCESS(cs.x, cs.y, 0);                    // tp = g      (P=slot0, Q=slot1)
      if (g != 44) PROCESS(cs.y, cs.x, 1);       // tp = 88-g   (P=slot1, Q=slot0)
    }
    __syncthreads();
  }

  // epilogue: singles t=0 / t=90, mask, scale
  const float* f0  = (const float*)(wsb + XF0_OFF)  + (size_t)b * DET;
  const float* f90 = (const float*)(wsb + XF90_OFF) + (size_t)b * DET;
  const float SC = (float)(PI_D / 360.0);
  int kx = 2*X1 - 511, ky = 2*Y1 - 511;
  bool in = (kx*kx + ky*ky) <= 261632;            // symmetric across all 8 outputs

  float g0x1 = f0[X1], g0x2 = f0[X2];
  float g90y1 = f90[Y1], g90y2 = f90[Y2];
  float P1 = A1 + g0x1 + g90y2;
  float P2 = A2 + g0x2 + g90y2;
  float P3 = A3 + g0x2 + g90y1;
  float P4 = A4 + g0x1 + g90y1;
  ob[(size_t)Y1*DET + X1] = in ? P1*SC : 0.f;
  ob[(size_t)Y1*DET + X2] = in ? P2*SC : 0.f;
  ob[(size_t)Y2*DET + X2] = in ? P3*SC : 0.f;
  ob[(size_t)Y2*DET + X1] = in ? P4*SC : 0.f;

  if (doQ) {
    float g0y1 = f0[Y1], g0y2 = f0[Y2];
    float g90x1 = f90[X1], g90x2 = f90[X2];
    float Q1 = B1 + g0y1 + g90x2;
    float Q2 = B2 + g0y1 + g90x1;
    float Q3 = B3 + g0y2 + g90x1;
    float Q4 = B4 + g0y2 + g90x2;
    Q1 = in ? Q1*SC : 0.f;
    Q2 = in ? Q2*SC : 0.f;
    Q3 = in ? Q3*SC : 0.f;
    Q4 = in ? Q4*SC : 0.f;
    __syncthreads();                                // pk free now
    float* qs = (float*)&pk[0][0];                  // [4][16][17] padded
    qs[(0*16 + lx)*17 + ly] = Q1;
    qs[(1*16 + lx)*17 + ly] = Q2;
    qs[(2*16 + lx)*17 + ly] = Q3;
    qs[(3*16 + lx)*17 + ly] = Q4;
    __syncthreads();
    float o1 = qs[(0*16 + ly)*17 + lx];
    float o2 = qs[(1*16 + ly)*17 + lx];
    float o3 = qs[(2*16 + ly)*17 + lx];
    float o4 = qs[(3*16 + ly)*17 + lx];
    int r1 = tx + ly, r2 = 511 - r1;
    int c1 = ty + lx, c2 = 511 - c1;
    ob[(size_t)r1*DET + c1] = o1;   // Q1: rows X1, cols Y1
    ob[(size_t)r2*DET + c1] = o2;   // Q2: rows X2, cols Y1
    ob[(size_t)r2*DET + c2] = o3;   // Q3: rows X2, cols Y2
    ob[(size_t)r1*DET + c2] = o4;   // Q4: rows X1, cols Y2
  }
}

extern "C" void kernel_launch(void* const* d_in, const int* in_sizes, int n_in,
                              void* d_out, int out_size, void* d_ws, size_t ws_size,
                              hipStream_t stream) {
  (void)in_sizes; (void)n_in; (void)out_size; (void)ws_size;
  const float* x = (const float*)d_in[0];
  float* out = (float*)d_out;
  char*  wsb = (char*)d_ws;

  filter_kernel<<<dim3(12, 16, 4), 256, 0, stream>>>(x, wsb);
  backproj_kernel<<<dim3(NUNIT + 1, 16), 256, 0, stream>>>(wsb, out);
}